// Round 1
// 1036.413 us; speedup vs baseline: 1.1392x; 1.1392x over previous
//
#include <hip/hip_runtime.h>
#include <stdint.h>

namespace {

constexpr int BROWS = 1024;   // batch
constexpr int NIT   = 50000;  // n_items
constexpr int NH1   = 600;
constexpr int NH2   = 200;
constexpr int KXP   = 50016;  // NIT padded to x32 (K of gemm1)
constexpr int N1P   = 640;    // NH1 padded to x128 (N of gemm1)
constexpr int NEP   = 50048;  // NIT padded to x128 (N of gemm4)
constexpr int KEP   = 608;    // NH1 padded to x32  (K of gemm4)
constexpr int KI_TOTAL = KXP / 32;  // 1563 k-steps of 32

typedef _Float16 f16x8 __attribute__((ext_vector_type(8)));
typedef _Float16 f16x4 __attribute__((ext_vector_type(4)));
typedef _Float16 f16x2 __attribute__((ext_vector_type(2)));
typedef float    f32x4 __attribute__((ext_vector_type(4)));

__device__ __forceinline__ void gld16(const void* g, void* l) {
  // async global->LDS, 16B per lane; LDS dest must be uniform-base + lane*16
  __builtin_amdgcn_global_load_lds(
      (__attribute__((address_space(1))) void*)(void*)g,
      (__attribute__((address_space(3))) void*)l, 16, 0, 0);
}

// ----------------------- row norms of x; optionally also write xh = (f16)x
// (unscaled; invnorm applied in reduce_epi1 — conversion is norm-independent
// so this stays a single pass over x)
__global__ __launch_bounds__(256) void norm_conv_k(const float* __restrict__ x,
                                                   float* __restrict__ invnorm,
                                                   _Float16* __restrict__ xh) {
  const int row = blockIdx.x;
  const float4* xr = (const float4*)(x + (size_t)row * NIT);
  float ss = 0.f;
  if (xh != nullptr) {
    f16x4* xo = (f16x4*)(xh + (size_t)row * KXP);
    for (int i = threadIdx.x; i < NIT / 4; i += 256) {
      float4 v = xr[i];
      ss += v.x * v.x + v.y * v.y + v.z * v.z + v.w * v.w;
      f16x4 h;
      h.x = (_Float16)v.x; h.y = (_Float16)v.y;
      h.z = (_Float16)v.z; h.w = (_Float16)v.w;
      xo[i] = h;
    }
    // pad k = 50000..50015 with zeros (KXP/4 - NIT/4 = 4 chunks)
    if (threadIdx.x < (KXP - NIT) / 4) {
      f16x4 z;
      z.x = (_Float16)0.f; z.y = (_Float16)0.f;
      z.z = (_Float16)0.f; z.w = (_Float16)0.f;
      xo[NIT / 4 + threadIdx.x] = z;
    }
  } else {
    for (int i = threadIdx.x; i < NIT / 4; i += 256) {
      float4 v = xr[i];
      ss += v.x * v.x + v.y * v.y + v.z * v.z + v.w * v.w;
    }
  }
  for (int o = 32; o > 0; o >>= 1) ss += __shfl_down(ss, o);
  __shared__ float red[4];
  if ((threadIdx.x & 63) == 0) red[threadIdx.x >> 6] = ss;
  __syncthreads();
  if (threadIdx.x == 0) {
    float s = red[0] + red[1] + red[2] + red[3];
    invnorm[row] = 1.0f / fmaxf(sqrtf(s), 1e-12f);
  }
}

// ------------------------------------------- W1 [K,N] -> W1T f16 [N1P][KXP]
// 64x64 tile; stores packed f16x2 so each 32-lane run writes 128B contiguous
__global__ __launch_bounds__(256) void transpose_w1_k(const float* __restrict__ W1,
                                                      _Float16* __restrict__ W1T) {
  __shared__ float tile[64][65];
  const int kb = blockIdx.x * 64;
  const int nb = blockIdx.y * 64;
  const int t = threadIdx.x;
  #pragma unroll
  for (int i = 0; i < 16; ++i) {
    int idx = i * 256 + t;
    int k = idx >> 6, n = idx & 63;
    int gk = kb + k, gn = nb + n;
    tile[k][n] = (gk < NIT && gn < NH1) ? W1[(size_t)gk * NH1 + gn] : 0.f;
  }
  __syncthreads();
  #pragma unroll
  for (int i = 0; i < 8; ++i) {
    int idx = i * 256 + t;        // 0..2047
    int n = idx >> 5;             // 0..63
    int k2 = (idx & 31) * 2;      // 0..62 (even)
    if (kb + k2 < KXP) {
      f16x2 h;
      h.x = (_Float16)tile[k2][n];
      h.y = (_Float16)tile[k2 + 1][n];
      *(f16x2*)(&W1T[(size_t)(nb + n) * KXP + kb + k2]) = h;
    }
  }
}

// ---------------------------- item_emb -> f16 [NEP][KEP] (+ fp32 row norms^2)
__global__ __launch_bounds__(256) void prep_emb_k(const float* __restrict__ emb,
                                                  _Float16* __restrict__ embb,
                                                  float* __restrict__ esq) {
  const int row = blockIdx.x * 4 + (threadIdx.x >> 6);
  const int lane = threadIdx.x & 63;
  const float* er = emb + (size_t)row * NH1;
  float ss = 0.f;
  #pragma unroll
  for (int j = 0; j < 10; ++j) {
    int idx = lane + 64 * j;
    float v = (row < NIT && idx < NH1) ? er[idx] : 0.f;
    ss += v * v;
    if (idx < KEP) embb[(size_t)row * KEP + idx] = (_Float16)v;
  }
  for (int o = 32; o > 0; o >>= 1) ss += __shfl_down(ss, o);
  if (lane == 0) esq[row] = ss;
}

// -------------------------------------------------- MFMA NT GEMM, 128x128x32
// MODE 0: C1-partial = x(fp32, reg-staged+cvt) @ W1T^T, split-K (gridDim.z)
// MODE 2: C1-partial = xh(f16, gld16-staged)  @ W1T^T, split-K (gridDim.z)
// MODE 1: dist       = hsq[m] - 2*(h3 @ emb^T) + esq[n]  -> d_out
template <int MODE>
__global__ __launch_bounds__(256) void mfma_nt_k(
    const void* __restrict__ Av, const _Float16* __restrict__ Bg,
    float* __restrict__ Cout, const float* __restrict__ hsq,
    const float* __restrict__ esq) {
  __shared__ _Float16 As[128 * 32];
  __shared__ _Float16 Bs[128 * 32];

  const int t = threadIdx.x;
  const int n0 = blockIdx.x * 128;
  const int m0 = blockIdx.y * 128;

  int ki0, ki1, lda, ldb;
  if (MODE == 1) {
    ki0 = 0; ki1 = KEP / 32; lda = KEP; ldb = KEP;
  } else {
    const int Z = (int)gridDim.z;
    const int kiPer = (KI_TOTAL + Z - 1) / Z;
    ki0 = blockIdx.z * kiPer;
    ki1 = ki0 + kiPer;
    if (ki1 > KI_TOTAL) ki1 = KI_TOTAL;
    lda = (MODE == 0) ? NIT : KXP;
    ldb = KXP;
  }

  const int lane = t & 63;
  const int wid = t >> 6;
  const int wm = wid >> 1, wn = wid & 1;
  const int lrow = lane & 15, quad = lane >> 4;

  const f32x4 zero = {0.f, 0.f, 0.f, 0.f};
  f32x4 acc[4][4];
  #pragma unroll
  for (int i = 0; i < 4; ++i)
    #pragma unroll
    for (int j = 0; j < 4; ++j) acc[i][j] = zero;

  for (int ki = ki0; ki < ki1; ++ki) {
    const int k0 = ki * 32;
    // ---- stage A tile [128 rows][32 k] ----
    if (MODE == 0) {
      const float* A = (const float*)Av;
      #pragma unroll
      for (int j = 0; j < 4; ++j) {
        int g = j * 256 + t;     // float4-chunk id, 0..1023
        int row = g >> 3;        // 0..127
        int kq = (g & 7) * 4;    // 0..28
        float4 v = {0.f, 0.f, 0.f, 0.f};
        if (k0 + kq < NIT)
          v = *(const float4*)(A + (size_t)(m0 + row) * lda + (k0 + kq));
        f16x4 h;
        h.x = (_Float16)v.x; h.y = (_Float16)v.y;
        h.z = (_Float16)v.z; h.w = (_Float16)v.w;
        *(f16x4*)(&As[row * 32 + kq]) = h;
      }
    } else {
      const _Float16* A = (const _Float16*)Av;
      #pragma unroll
      for (int j = 0; j < 2; ++j) {
        int c = j * 256 + t;
        int row = c >> 2, kk = (c & 3) * 8;
        gld16(A + (size_t)(m0 + row) * lda + (k0 + kk), &As[c * 8]);
      }
    }
    // ---- stage B tile [128 n][32 k] ----
    #pragma unroll
    for (int j = 0; j < 2; ++j) {
      int c = j * 256 + t;
      int row = c >> 2, kk = (c & 3) * 8;
      gld16(Bg + (size_t)(n0 + row) * ldb + (k0 + kk), &Bs[c * 8]);
    }
    __syncthreads();

    f16x8 af[4], bfr[4];
    #pragma unroll
    for (int mi = 0; mi < 4; ++mi)
      af[mi] = *(const f16x8*)(&As[(wm * 64 + mi * 16 + lrow) * 32 + quad * 8]);
    #pragma unroll
    for (int ni = 0; ni < 4; ++ni)
      bfr[ni] = *(const f16x8*)(&Bs[(wn * 64 + ni * 16 + lrow) * 32 + quad * 8]);
    #pragma unroll
    for (int mi = 0; mi < 4; ++mi)
      #pragma unroll
      for (int ni = 0; ni < 4; ++ni)
        acc[mi][ni] = __builtin_amdgcn_mfma_f32_16x16x32_f16(af[mi], bfr[ni],
                                                             acc[mi][ni], 0, 0, 0);
    __syncthreads();
  }

  // ---- epilogue; C/D layout: col = lane&15, row = (lane>>4)*4 + reg ----
  if (MODE != 1) {
    float* Cs = Cout + (size_t)blockIdx.z * BROWS * N1P;
    #pragma unroll
    for (int mi = 0; mi < 4; ++mi)
      #pragma unroll
      for (int r = 0; r < 4; ++r) {
        int row = m0 + wm * 64 + mi * 16 + quad * 4 + r;
        #pragma unroll
        for (int ni = 0; ni < 4; ++ni) {
          int col = n0 + wn * 64 + ni * 16 + lrow;
          Cs[(size_t)row * N1P + col] = acc[mi][ni][r];
        }
      }
  } else {
    #pragma unroll
    for (int mi = 0; mi < 4; ++mi)
      #pragma unroll
      for (int r = 0; r < 4; ++r) {
        int row = m0 + wm * 64 + mi * 16 + quad * 4 + r;
        float hv = hsq[row];
        #pragma unroll
        for (int ni = 0; ni < 4; ++ni) {
          int col = n0 + wn * 64 + ni * 16 + lrow;
          if (col < NIT)
            Cout[(size_t)row * NIT + col] = hv - 2.f * acc[mi][ni][r] + esq[col];
        }
      }
  }
}

// ------------------------- sum split-K slabs, scale by invnorm, +b1, tanh
__global__ __launch_bounds__(256) void reduce_epi1_k(const float* __restrict__ C1p,
                                                     const float* __restrict__ invnorm,
                                                     const float* __restrict__ b1,
                                                     float* __restrict__ h1,
                                                     int nslabs) {
  int idx = blockIdx.x * 256 + threadIdx.x;
  if (idx >= BROWS * NH1) return;
  int m = idx / NH1, n = idx - m * NH1;
  float s = 0.f;
  for (int sp = 0; sp < nslabs; ++sp)
    s += C1p[(size_t)sp * BROWS * N1P + (size_t)m * N1P + n];
  h1[idx] = tanhf(invnorm[m] * s + b1[n]);
}

// ------------------------------------------------ h2 = tanh(h1 @ W2 + b2)
__global__ __launch_bounds__(256) void gemm2_k(const float* __restrict__ h1,
                                               const float* __restrict__ W2,
                                               const float* __restrict__ b2,
                                               float* __restrict__ h2) {
  __shared__ float hs[8 * NH1];
  const int m0 = blockIdx.x * 8;
  const int t = threadIdx.x;
  for (int i = t; i < 8 * NH1; i += 256) hs[i] = h1[(size_t)m0 * NH1 + i];
  __syncthreads();
  if (t < NH2) {
    float acc[8];
    #pragma unroll
    for (int r = 0; r < 8; ++r) acc[r] = 0.f;
    for (int k = 0; k < NH1; ++k) {
      float w = W2[k * NH2 + t];
      #pragma unroll
      for (int r = 0; r < 8; ++r) acc[r] += hs[r * NH1 + k] * w;
    }
    float bb = b2[t];
    #pragma unroll
    for (int r = 0; r < 8; ++r) h2[(size_t)(m0 + r) * NH2 + t] = tanhf(acc[r] + bb);
  }
}

// --------------------- h3 = tanh(h2 @ W3 + b3) -> f16 [BROWS][KEP] + hsq
__global__ __launch_bounds__(256) void gemm3_k(const float* __restrict__ h2,
                                               const float* __restrict__ W3,
                                               const float* __restrict__ b3,
                                               _Float16* __restrict__ h3h,
                                               float* __restrict__ hsq) {
  __shared__ float hs[8 * NH2];
  const int m0 = blockIdx.x * 8;
  const int t = threadIdx.x;
  for (int i = t; i < 8 * NH2; i += 256) hs[i] = h2[(size_t)m0 * NH2 + i];
  __syncthreads();
  float ssq[8];
  #pragma unroll
  for (int r = 0; r < 8; ++r) ssq[r] = 0.f;
  for (int c = 0; c < 3; ++c) {
    int n = t + c * 256;
    if (n < NH1) {
      float acc[8];
      #pragma unroll
      for (int r = 0; r < 8; ++r) acc[r] = 0.f;
      for (int k = 0; k < NH2; ++k) {
        float w = W3[k * NH1 + n];
        #pragma unroll
        for (int r = 0; r < 8; ++r) acc[r] += hs[r * NH2 + k] * w;
      }
      float bb = b3[n];
      #pragma unroll
      for (int r = 0; r < 8; ++r) {
        float v = tanhf(acc[r] + bb);
        h3h[(size_t)(m0 + r) * KEP + n] = (_Float16)v;
        ssq[r] += v * v;
      }
    } else if (n < KEP) {
      #pragma unroll
      for (int r = 0; r < 8; ++r) h3h[(size_t)(m0 + r) * KEP + n] = (_Float16)0.f;
    }
  }
  // wave-shuffle reduce of 8 row-sums, then cross-wave via tiny LDS
  const int lane = t & 63, wid = t >> 6;
  #pragma unroll
  for (int r = 0; r < 8; ++r)
    for (int o = 32; o > 0; o >>= 1) ssq[r] += __shfl_down(ssq[r], o);
  __shared__ float red2[8][4];
  if (lane == 0) {
    #pragma unroll
    for (int r = 0; r < 8; ++r) red2[r][wid] = ssq[r];
  }
  __syncthreads();
  if (t < 8) hsq[m0 + t] = red2[t][0] + red2[t][1] + red2[t][2] + red2[t][3];
}

}  // namespace

extern "C" void kernel_launch(void* const* d_in, const int* in_sizes, int n_in,
                              void* d_out, int out_size, void* d_ws, size_t ws_size,
                              hipStream_t stream) {
  const float* x   = (const float*)d_in[0];
  const float* W1  = (const float*)d_in[1];
  const float* b1  = (const float*)d_in[2];
  const float* W2  = (const float*)d_in[3];
  const float* b2  = (const float*)d_in[4];
  const float* W3  = (const float*)d_in[5];
  const float* b3  = (const float*)d_in[6];
  const float* emb = (const float*)d_in[7];
  float* out = (float*)d_out;

  char* ws = (char*)d_ws;

  // sizes (all multiples of 256B)
  const size_t XHSZ  = (size_t)BROWS * KXP * 2;   // 102,432,768 (f16 x, k-padded)
  const size_t W1TSZ = (size_t)N1P * KXP * 2;     //  64,020,480
  const size_t SLAB  = (size_t)BROWS * N1P * 4;   //   2,621,440 per split slab
  const size_t TAIL  = 4096 + 200192 + 2457600 + 819200 + 1245184 + 4096;

  // ---- plan selection from ws_size: prefer f16-A (gld16 staging) + splits
  // up to 32 (5 blocks/CU); fall back to f32-A staging with as many splits
  // as fit (floor 8 == previously-verified layout).
  bool useF16A;
  int S;
  const size_t baseA = XHSZ + W1TSZ + TAIL;   // ~171.2 MB
  const size_t baseB = W1TSZ + TAIL;          //  ~68.8 MB
  if (ws_size >= baseA + 16 * SLAB) {
    useF16A = true;
    size_t s = (ws_size - baseA) / SLAB;
    S = s > 32 ? 32 : (int)s;
  } else if (ws_size >= baseB + 8 * SLAB) {
    useF16A = false;
    size_t s = (ws_size - baseB) / SLAB;
    S = s > 32 ? 32 : (int)s;
  } else {
    return;  // ws too small -> fail visibly (poison output)
  }

  size_t off = 0;
  _Float16* xh = nullptr;
  if (useF16A) { xh = (_Float16*)(ws + off); off += XHSZ; }
  const size_t oW1T = off;
  _Float16* W1T = (_Float16*)(ws + off); off += W1TSZ;
  float* C1p = (float*)(ws + off); off += (size_t)S * SLAB;
  float* invn = (float*)(ws + off); off += 4096;
  float* esq  = (float*)(ws + off); off += 200192;
  float* h1   = (float*)(ws + off); off += 2457600;
  float* h2   = (float*)(ws + off); off += 819200;
  _Float16* h3h = (_Float16*)(ws + off); off += 1245184;
  float* hsq  = (float*)(ws + off); off += 4096;
  _Float16* embb = (_Float16*)(ws + oW1T);  // aliases W1T (dead after gemm1)

  norm_conv_k<<<dim3(BROWS), dim3(256), 0, stream>>>(x, invn, xh);
  transpose_w1_k<<<dim3((KXP + 63) / 64, N1P / 64), dim3(256), 0, stream>>>(W1, W1T);
  if (useF16A) {
    mfma_nt_k<2><<<dim3(N1P / 128, BROWS / 128, S), dim3(256), 0, stream>>>(
        (const void*)xh, W1T, C1p, nullptr, nullptr);
  } else {
    mfma_nt_k<0><<<dim3(N1P / 128, BROWS / 128, S), dim3(256), 0, stream>>>(
        (const void*)x, W1T, C1p, nullptr, nullptr);
  }
  reduce_epi1_k<<<dim3((BROWS * NH1 + 255) / 256), dim3(256), 0, stream>>>(
      C1p, invn, b1, h1, S);
  prep_emb_k<<<dim3(NEP / 4), dim3(256), 0, stream>>>(emb, embb, esq);
  gemm2_k<<<dim3(BROWS / 8), dim3(256), 0, stream>>>(h1, W2, b2, h2);
  gemm3_k<<<dim3(BROWS / 8), dim3(256), 0, stream>>>(h2, W3, b3, h3h, hsq);
  mfma_nt_k<1><<<dim3(NEP / 128, BROWS / 128, 1), dim3(256), 0, stream>>>(
      (const void*)h3h, embb, out, hsq, esq);
}

// Round 2
// 1009.612 us; speedup vs baseline: 1.1694x; 1.0265x over previous
//
#include <hip/hip_runtime.h>
#include <stdint.h>

namespace {

constexpr int BROWS = 1024;   // batch
constexpr int NIT   = 50000;  // n_items
constexpr int NH1   = 600;
constexpr int NH2   = 200;
constexpr int KXP   = 50048;  // NIT padded to x64 (K of gemm1)
constexpr int N1P   = 640;    // NH1 padded to x128 (N of gemm1)
constexpr int NEP   = 50048;  // NIT padded to x128 (N of gemm4)
constexpr int KEP   = 608;    // NH1 padded to x32  (K of gemm4)
constexpr int KI_TOTAL = KXP / 32;  // 1564 k-steps of 32

typedef _Float16 f16x8 __attribute__((ext_vector_type(8)));
typedef _Float16 f16x4 __attribute__((ext_vector_type(4)));
typedef _Float16 f16x2 __attribute__((ext_vector_type(2)));
typedef float    f32x4 __attribute__((ext_vector_type(4)));

__device__ __forceinline__ void gld16(const void* g, void* l) {
  // async global->LDS, 16B per lane; LDS dest must be uniform-base + lane*16
  __builtin_amdgcn_global_load_lds(
      (__attribute__((address_space(1))) void*)(void*)g,
      (__attribute__((address_space(3))) void*)l, 16, 0, 0);
}

// ----------------------- row norms of x; optionally also write xh = (f16)x
// (unscaled; invnorm applied in reduce_epi1 — conversion is norm-independent
// so this stays a single pass over x)
__global__ __launch_bounds__(256) void norm_conv_k(const float* __restrict__ x,
                                                   float* __restrict__ invnorm,
                                                   _Float16* __restrict__ xh) {
  const int row = blockIdx.x;
  const float4* xr = (const float4*)(x + (size_t)row * NIT);
  float ss = 0.f;
  if (xh != nullptr) {
    f16x4* xo = (f16x4*)(xh + (size_t)row * KXP);
    #pragma unroll 4
    for (int i = threadIdx.x; i < NIT / 4; i += 256) {
      float4 v = xr[i];
      ss += v.x * v.x + v.y * v.y + v.z * v.z + v.w * v.w;
      f16x4 h;
      h.x = (_Float16)v.x; h.y = (_Float16)v.y;
      h.z = (_Float16)v.z; h.w = (_Float16)v.w;
      xo[i] = h;
    }
    // pad k = 50000..50047 with zeros ((KXP-NIT)/4 = 12 chunks)
    if (threadIdx.x < (KXP - NIT) / 4) {
      f16x4 z;
      z.x = (_Float16)0.f; z.y = (_Float16)0.f;
      z.z = (_Float16)0.f; z.w = (_Float16)0.f;
      xo[NIT / 4 + threadIdx.x] = z;
    }
  } else {
    #pragma unroll 4
    for (int i = threadIdx.x; i < NIT / 4; i += 256) {
      float4 v = xr[i];
      ss += v.x * v.x + v.y * v.y + v.z * v.z + v.w * v.w;
    }
  }
  for (int o = 32; o > 0; o >>= 1) ss += __shfl_down(ss, o);
  __shared__ float red[4];
  if ((threadIdx.x & 63) == 0) red[threadIdx.x >> 6] = ss;
  __syncthreads();
  if (threadIdx.x == 0) {
    float s = red[0] + red[1] + red[2] + red[3];
    invnorm[row] = 1.0f / fmaxf(sqrtf(s), 1e-12f);
  }
}

// ------------------------------------------- W1 [K,N] -> W1T f16 [N1P][KXP]
// 64x64 tile; stores packed f16x2 so each 32-lane run writes 128B contiguous
__global__ __launch_bounds__(256) void transpose_w1_k(const float* __restrict__ W1,
                                                      _Float16* __restrict__ W1T) {
  __shared__ float tile[64][65];
  const int kb = blockIdx.x * 64;
  const int nb = blockIdx.y * 64;
  const int t = threadIdx.x;
  #pragma unroll
  for (int i = 0; i < 16; ++i) {
    int idx = i * 256 + t;
    int k = idx >> 6, n = idx & 63;
    int gk = kb + k, gn = nb + n;
    tile[k][n] = (gk < NIT && gn < NH1) ? W1[(size_t)gk * NH1 + gn] : 0.f;
  }
  __syncthreads();
  #pragma unroll
  for (int i = 0; i < 8; ++i) {
    int idx = i * 256 + t;        // 0..2047
    int n = idx >> 5;             // 0..63
    int k2 = (idx & 31) * 2;      // 0..62 (even)
    f16x2 h;
    h.x = (_Float16)tile[k2][n];
    h.y = (_Float16)tile[k2 + 1][n];
    *(f16x2*)(&W1T[(size_t)(nb + n) * KXP + kb + k2]) = h;
  }
}

// ---------------------------- item_emb -> f16 [NEP][KEP] (+ fp32 row norms^2)
__global__ __launch_bounds__(256) void prep_emb_k(const float* __restrict__ emb,
                                                  _Float16* __restrict__ embb,
                                                  float* __restrict__ esq) {
  const int row = blockIdx.x * 4 + (threadIdx.x >> 6);
  const int lane = threadIdx.x & 63;
  const float* er = emb + (size_t)row * NH1;
  float ss = 0.f;
  #pragma unroll
  for (int j = 0; j < 10; ++j) {
    int idx = lane + 64 * j;
    float v = (row < NIT && idx < NH1) ? er[idx] : 0.f;
    ss += v * v;
    if (idx < KEP) embb[(size_t)row * KEP + idx] = (_Float16)v;
  }
  for (int o = 32; o > 0; o >>= 1) ss += __shfl_down(ss, o);
  if (lane == 0) esq[row] = ss;
}

// -------------------------------------------------- MFMA NT GEMM, 128x128x32
// Double-buffered 2-phase pipeline (T3 minimum recipe): stage(next) issued
// BEFORE compute(cur); ONE __syncthreads per K-step (drains vmcnt+lgkmcnt).
// MODE 0: C1-partial = x(fp32, reg-staged+cvt) @ W1T^T, split-K (gridDim.z)
// MODE 2: C1-partial = xh(f16, gld16-staged)  @ W1T^T, split-K (gridDim.z)
// MODE 1: dist       = hsq[m] - 2*(h3 @ emb^T) + esq[n]  -> d_out
template <int MODE>
__global__ __launch_bounds__(256, 4) void mfma_nt_k(
    const void* __restrict__ Av, const _Float16* __restrict__ Bg,
    float* __restrict__ Cout, const float* __restrict__ hsq,
    const float* __restrict__ esq) {
  __shared__ _Float16 As[2][128 * 32];
  __shared__ _Float16 Bs[2][128 * 32];

  const int t = threadIdx.x;
  const int n0 = blockIdx.x * 128;
  const int m0 = blockIdx.y * 128;

  int ki0, ki1, lda, ldb;
  if (MODE == 1) {
    ki0 = 0; ki1 = KEP / 32; lda = KEP; ldb = KEP;
  } else {
    const int Z = (int)gridDim.z;
    const int kiPer = (KI_TOTAL + Z - 1) / Z;
    ki0 = blockIdx.z * kiPer;
    ki1 = ki0 + kiPer;
    if (ki1 > KI_TOTAL) ki1 = KI_TOTAL;
    lda = (MODE == 0) ? NIT : KXP;
    ldb = KXP;
  }

  const int lane = t & 63;
  const int wid = t >> 6;
  const int wm = wid >> 1, wn = wid & 1;
  const int lrow = lane & 15, quad = lane >> 4;

  const f32x4 zero = {0.f, 0.f, 0.f, 0.f};
  f32x4 acc[4][4];
  #pragma unroll
  for (int i = 0; i < 4; ++i)
    #pragma unroll
    for (int j = 0; j < 4; ++j) acc[i][j] = zero;

  // ---- staging helpers ----
  auto stage = [&](int buf, int ki) {
    const int k0 = ki * 32;
    if (MODE == 0) {
      const float* A = (const float*)Av;
      #pragma unroll
      for (int j = 0; j < 4; ++j) {
        int g = j * 256 + t;     // float4-chunk id, 0..1023
        int row = g >> 3;        // 0..127
        int kq = (g & 7) * 4;    // 0..28
        float4 v = {0.f, 0.f, 0.f, 0.f};
        if (k0 + kq < NIT)
          v = *(const float4*)(A + (size_t)(m0 + row) * lda + (k0 + kq));
        f16x4 h;
        h.x = (_Float16)v.x; h.y = (_Float16)v.y;
        h.z = (_Float16)v.z; h.w = (_Float16)v.w;
        *(f16x4*)(&As[buf][row * 32 + kq]) = h;
      }
    } else {
      const _Float16* A = (const _Float16*)Av;
      #pragma unroll
      for (int j = 0; j < 2; ++j) {
        int c = j * 256 + t;
        int row = c >> 2, kk = (c & 3) * 8;
        gld16(A + (size_t)(m0 + row) * lda + (k0 + kk), &As[buf][c * 8]);
      }
    }
    #pragma unroll
    for (int j = 0; j < 2; ++j) {
      int c = j * 256 + t;
      int row = c >> 2, kk = (c & 3) * 8;
      gld16(Bg + (size_t)(n0 + row) * ldb + (k0 + kk), &Bs[buf][c * 8]);
    }
  };

  // ---- prologue: fill buf0, drain, then pipeline ----
  stage(0, ki0);
  __syncthreads();

  int cur = 0;
  for (int ki = ki0; ki < ki1; ++ki) {
    if (ki + 1 < ki1) stage(cur ^ 1, ki + 1);  // async loads of next tile

    f16x8 af[4], bfr[4];
    #pragma unroll
    for (int mi = 0; mi < 4; ++mi)
      af[mi] = *(const f16x8*)(&As[cur][(wm * 64 + mi * 16 + lrow) * 32 + quad * 8]);
    #pragma unroll
    for (int ni = 0; ni < 4; ++ni)
      bfr[ni] = *(const f16x8*)(&Bs[cur][(wn * 64 + ni * 16 + lrow) * 32 + quad * 8]);
    #pragma unroll
    for (int mi = 0; mi < 4; ++mi)
      #pragma unroll
      for (int ni = 0; ni < 4; ++ni)
        acc[mi][ni] = __builtin_amdgcn_mfma_f32_16x16x32_f16(af[mi], bfr[ni],
                                                             acc[mi][ni], 0, 0, 0);
    __syncthreads();  // drains vmcnt(0)+lgkmcnt(0): next tile resident, cur free
    cur ^= 1;
  }

  // ---- epilogue; C/D layout: col = lane&15, row = (lane>>4)*4 + reg ----
  if (MODE != 1) {
    float* Cs = Cout + (size_t)blockIdx.z * BROWS * N1P;
    #pragma unroll
    for (int mi = 0; mi < 4; ++mi)
      #pragma unroll
      for (int r = 0; r < 4; ++r) {
        int row = m0 + wm * 64 + mi * 16 + quad * 4 + r;
        #pragma unroll
        for (int ni = 0; ni < 4; ++ni) {
          int col = n0 + wn * 64 + ni * 16 + lrow;
          Cs[(size_t)row * N1P + col] = acc[mi][ni][r];
        }
      }
  } else {
    #pragma unroll
    for (int mi = 0; mi < 4; ++mi)
      #pragma unroll
      for (int r = 0; r < 4; ++r) {
        int row = m0 + wm * 64 + mi * 16 + quad * 4 + r;
        float hv = hsq[row];
        #pragma unroll
        for (int ni = 0; ni < 4; ++ni) {
          int col = n0 + wn * 64 + ni * 16 + lrow;
          if (col < NIT)
            Cout[(size_t)row * NIT + col] = hv - 2.f * acc[mi][ni][r] + esq[col];
        }
      }
  }
}

// ------------------------- sum split-K slabs, scale by invnorm, +b1, tanh
__global__ __launch_bounds__(256) void reduce_epi1_k(const float* __restrict__ C1p,
                                                     const float* __restrict__ invnorm,
                                                     const float* __restrict__ b1,
                                                     float* __restrict__ h1,
                                                     int nslabs) {
  int idx = blockIdx.x * 256 + threadIdx.x;
  if (idx >= BROWS * NH1) return;
  int m = idx / NH1, n = idx - m * NH1;
  float s = 0.f;
  for (int sp = 0; sp < nslabs; ++sp)
    s += C1p[(size_t)sp * BROWS * N1P + (size_t)m * N1P + n];
  h1[idx] = tanhf(invnorm[m] * s + b1[n]);
}

// ------------------------------------------------ h2 = tanh(h1 @ W2 + b2)
// k-loop unrolled x8 so 8 W2 loads are in flight (was latency-serial)
__global__ __launch_bounds__(256) void gemm2_k(const float* __restrict__ h1,
                                               const float* __restrict__ W2,
                                               const float* __restrict__ b2,
                                               float* __restrict__ h2) {
  __shared__ float hs[8 * NH1];
  const int m0 = blockIdx.x * 8;
  const int t = threadIdx.x;
  for (int i = t; i < 8 * NH1; i += 256) hs[i] = h1[(size_t)m0 * NH1 + i];
  __syncthreads();
  if (t < NH2) {
    float acc[8];
    #pragma unroll
    for (int r = 0; r < 8; ++r) acc[r] = 0.f;
    for (int k0 = 0; k0 < NH1; k0 += 8) {   // 600 = 75 * 8
      float w[8];
      #pragma unroll
      for (int u = 0; u < 8; ++u) w[u] = W2[(k0 + u) * NH2 + t];
      #pragma unroll
      for (int u = 0; u < 8; ++u)
        #pragma unroll
        for (int r = 0; r < 8; ++r) acc[r] += hs[r * NH1 + k0 + u] * w[u];
    }
    float bb = b2[t];
    #pragma unroll
    for (int r = 0; r < 8; ++r) h2[(size_t)(m0 + r) * NH2 + t] = tanhf(acc[r] + bb);
  }
}

// --------------------- h3 = tanh(h2 @ W3 + b3) -> f16 [BROWS][KEP] + hsq
__global__ __launch_bounds__(256) void gemm3_k(const float* __restrict__ h2,
                                               const float* __restrict__ W3,
                                               const float* __restrict__ b3,
                                               _Float16* __restrict__ h3h,
                                               float* __restrict__ hsq) {
  __shared__ float hs[8 * NH2];
  const int m0 = blockIdx.x * 8;
  const int t = threadIdx.x;
  for (int i = t; i < 8 * NH2; i += 256) hs[i] = h2[(size_t)m0 * NH2 + i];
  __syncthreads();
  float ssq[8];
  #pragma unroll
  for (int r = 0; r < 8; ++r) ssq[r] = 0.f;
  for (int c = 0; c < 3; ++c) {
    int n = t + c * 256;
    if (n < NH1) {
      float acc[8];
      #pragma unroll
      for (int r = 0; r < 8; ++r) acc[r] = 0.f;
      for (int k0 = 0; k0 < NH2; k0 += 8) {  // 200 = 25 * 8
        float w[8];
        #pragma unroll
        for (int u = 0; u < 8; ++u) w[u] = W3[(k0 + u) * NH1 + n];
        #pragma unroll
        for (int u = 0; u < 8; ++u)
          #pragma unroll
          for (int r = 0; r < 8; ++r) acc[r] += hs[r * NH2 + k0 + u] * w[u];
      }
      float bb = b3[n];
      #pragma unroll
      for (int r = 0; r < 8; ++r) {
        float v = tanhf(acc[r] + bb);
        h3h[(size_t)(m0 + r) * KEP + n] = (_Float16)v;
        ssq[r] += v * v;
      }
    } else if (n < KEP) {
      #pragma unroll
      for (int r = 0; r < 8; ++r) h3h[(size_t)(m0 + r) * KEP + n] = (_Float16)0.f;
    }
  }
  // wave-shuffle reduce of 8 row-sums, then cross-wave via tiny LDS
  const int lane = t & 63, wid = t >> 6;
  #pragma unroll
  for (int r = 0; r < 8; ++r)
    for (int o = 32; o > 0; o >>= 1) ssq[r] += __shfl_down(ssq[r], o);
  __shared__ float red2[8][4];
  if (lane == 0) {
    #pragma unroll
    for (int r = 0; r < 8; ++r) red2[r][wid] = ssq[r];
  }
  __syncthreads();
  if (t < 8) hsq[m0 + t] = red2[t][0] + red2[t][1] + red2[t][2] + red2[t][3];
}

}  // namespace

extern "C" void kernel_launch(void* const* d_in, const int* in_sizes, int n_in,
                              void* d_out, int out_size, void* d_ws, size_t ws_size,
                              hipStream_t stream) {
  const float* x   = (const float*)d_in[0];
  const float* W1  = (const float*)d_in[1];
  const float* b1  = (const float*)d_in[2];
  const float* W2  = (const float*)d_in[3];
  const float* b2  = (const float*)d_in[4];
  const float* W3  = (const float*)d_in[5];
  const float* b3  = (const float*)d_in[6];
  const float* emb = (const float*)d_in[7];
  float* out = (float*)d_out;

  char* ws = (char*)d_ws;

  // sizes (all multiples of 256B)
  const size_t XHSZ  = (size_t)BROWS * KXP * 2;   // 102,498,304 (f16 x, k-padded)
  const size_t W1TSZ = (size_t)N1P * KXP * 2;     //  64,061,440
  const size_t SLAB  = (size_t)BROWS * N1P * 4;   //   2,621,440 per split slab
  const size_t TAIL  = 4096 + 200192 + 2457600 + 819200 + 1245184 + 4096;

  // ---- plan selection from ws_size: prefer f16-A (gld16 staging) + splits
  // up to 32 (5 blocks/CU); fall back to f32-A staging with as many splits
  // as fit (floor 8 == previously-verified layout).
  bool useF16A;
  int S;
  const size_t baseA = XHSZ + W1TSZ + TAIL;   // ~171.3 MB
  const size_t baseB = W1TSZ + TAIL;          //  ~68.9 MB
  if (ws_size >= baseA + 16 * SLAB) {
    useF16A = true;
    size_t s = (ws_size - baseA) / SLAB;
    S = s > 32 ? 32 : (int)s;
  } else if (ws_size >= baseB + 8 * SLAB) {
    useF16A = false;
    size_t s = (ws_size - baseB) / SLAB;
    S = s > 32 ? 32 : (int)s;
  } else {
    return;  // ws too small -> fail visibly (poison output)
  }

  size_t off = 0;
  _Float16* xh = nullptr;
  if (useF16A) { xh = (_Float16*)(ws + off); off += XHSZ; }
  const size_t oW1T = off;
  _Float16* W1T = (_Float16*)(ws + off); off += W1TSZ;
  float* C1p = (float*)(ws + off); off += (size_t)S * SLAB;
  float* invn = (float*)(ws + off); off += 4096;
  float* esq  = (float*)(ws + off); off += 200192;
  float* h1   = (float*)(ws + off); off += 2457600;
  float* h2   = (float*)(ws + off); off += 819200;
  _Float16* h3h = (_Float16*)(ws + off); off += 1245184;
  float* hsq  = (float*)(ws + off); off += 4096;
  _Float16* embb = (_Float16*)(ws + oW1T);  // aliases W1T (dead after gemm1)

  norm_conv_k<<<dim3(BROWS), dim3(256), 0, stream>>>(x, invn, xh);
  transpose_w1_k<<<dim3(KXP / 64, N1P / 64), dim3(256), 0, stream>>>(W1, W1T);
  if (useF16A) {
    mfma_nt_k<2><<<dim3(N1P / 128, BROWS / 128, S), dim3(256), 0, stream>>>(
        (const void*)xh, W1T, C1p, nullptr, nullptr);
  } else {
    mfma_nt_k<0><<<dim3(N1P / 128, BROWS / 128, S), dim3(256), 0, stream>>>(
        (const void*)x, W1T, C1p, nullptr, nullptr);
  }
  reduce_epi1_k<<<dim3((BROWS * NH1 + 255) / 256), dim3(256), 0, stream>>>(
      C1p, invn, b1, h1, S);
  prep_emb_k<<<dim3(NEP / 4), dim3(256), 0, stream>>>(emb, embb, esq);
  gemm2_k<<<dim3(BROWS / 8), dim3(256), 0, stream>>>(h1, W2, b2, h2);
  gemm3_k<<<dim3(BROWS / 8), dim3(256), 0, stream>>>(h2, W3, b3, h3h, hsq);
  mfma_nt_k<1><<<dim3(NEP / 128, BROWS / 128, 1), dim3(256), 0, stream>>>(
      (const void*)h3h, embb, out, hsq, esq);
}

// Round 3
// 863.476 us; speedup vs baseline: 1.3674x; 1.1692x over previous
//
#include <hip/hip_runtime.h>
#include <stdint.h>

namespace {

constexpr int BROWS = 1024;   // batch
constexpr int NIT   = 50000;  // n_items
constexpr int NH1   = 600;
constexpr int NH2   = 200;
constexpr int KXP   = 50048;  // NIT padded to x64 (K of gemm1)
constexpr int N1P   = 640;    // NH1 padded to x128 (N of gemm1)
constexpr int NEP   = 50048;  // NIT padded to x128 (N of gemm4)
constexpr int KEP   = 640;    // NH1 padded to x64  (K of gemm4)
constexpr int KI64_TOTAL = KXP / 64;  // 782 k-steps of 64
constexpr int NBLK1 = N1P / 128;      // 5  (gemm1 n-blocks)
constexpr int NBLK4 = NEP / 128;      // 391 (dist n-blocks)

typedef _Float16 f16x8 __attribute__((ext_vector_type(8)));
typedef _Float16 f16x4 __attribute__((ext_vector_type(4)));
typedef _Float16 f16x2 __attribute__((ext_vector_type(2)));
typedef float    f32x4 __attribute__((ext_vector_type(4)));

__device__ __forceinline__ void gld16(const void* g, void* l) {
  // async global->LDS, 16B per lane; LDS dest must be uniform-base + lane*16
  __builtin_amdgcn_global_load_lds(
      (__attribute__((address_space(1))) void*)(void*)g,
      (__attribute__((address_space(3))) void*)l, 16, 0, 0);
}

// ----------------------- row norms of x; optionally also write xh = (f16)x
__global__ __launch_bounds__(256) void norm_conv_k(const float* __restrict__ x,
                                                   float* __restrict__ invnorm,
                                                   _Float16* __restrict__ xh) {
  const int row = blockIdx.x;
  const float4* xr = (const float4*)(x + (size_t)row * NIT);
  float ss = 0.f;
  if (xh != nullptr) {
    f16x4* xo = (f16x4*)(xh + (size_t)row * KXP);
    #pragma unroll 4
    for (int i = threadIdx.x; i < NIT / 4; i += 256) {
      float4 v = xr[i];
      ss += v.x * v.x + v.y * v.y + v.z * v.z + v.w * v.w;
      f16x4 h;
      h.x = (_Float16)v.x; h.y = (_Float16)v.y;
      h.z = (_Float16)v.z; h.w = (_Float16)v.w;
      xo[i] = h;
    }
    if (threadIdx.x < (KXP - NIT) / 4) {  // pad k=50000..50047
      f16x4 z;
      z.x = (_Float16)0.f; z.y = (_Float16)0.f;
      z.z = (_Float16)0.f; z.w = (_Float16)0.f;
      xo[NIT / 4 + threadIdx.x] = z;
    }
  } else {
    #pragma unroll 4
    for (int i = threadIdx.x; i < NIT / 4; i += 256) {
      float4 v = xr[i];
      ss += v.x * v.x + v.y * v.y + v.z * v.z + v.w * v.w;
    }
  }
  for (int o = 32; o > 0; o >>= 1) ss += __shfl_down(ss, o);
  __shared__ float red[4];
  if ((threadIdx.x & 63) == 0) red[threadIdx.x >> 6] = ss;
  __syncthreads();
  if (threadIdx.x == 0) {
    float s = red[0] + red[1] + red[2] + red[3];
    invnorm[row] = 1.0f / fmaxf(sqrtf(s), 1e-12f);
  }
}

// ------------------------------------------- W1 [K,N] -> W1T f16 [N1P][KXP]
__global__ __launch_bounds__(256) void transpose_w1_k(const float* __restrict__ W1,
                                                      _Float16* __restrict__ W1T) {
  __shared__ float tile[64][65];
  const int kb = blockIdx.x * 64;
  const int nb = blockIdx.y * 64;
  const int t = threadIdx.x;
  #pragma unroll
  for (int i = 0; i < 16; ++i) {
    int idx = i * 256 + t;
    int k = idx >> 6, n = idx & 63;
    int gk = kb + k, gn = nb + n;
    tile[k][n] = (gk < NIT && gn < NH1) ? W1[(size_t)gk * NH1 + gn] : 0.f;
  }
  __syncthreads();
  #pragma unroll
  for (int i = 0; i < 8; ++i) {
    int idx = i * 256 + t;        // 0..2047
    int n = idx >> 5;             // 0..63
    int k2 = (idx & 31) * 2;      // 0..62 (even)
    f16x2 h;
    h.x = (_Float16)tile[k2][n];
    h.y = (_Float16)tile[k2 + 1][n];
    *(f16x2*)(&W1T[(size_t)(nb + n) * KXP + kb + k2]) = h;
  }
}

// ---------------------------- item_emb -> f16 [NEP][KEP] (+ fp32 row norms^2)
__global__ __launch_bounds__(256) void prep_emb_k(const float* __restrict__ emb,
                                                  _Float16* __restrict__ embb,
                                                  float* __restrict__ esq) {
  const int row = blockIdx.x * 4 + (threadIdx.x >> 6);
  const int lane = threadIdx.x & 63;
  const float* er = emb + (size_t)row * NH1;
  float ss = 0.f;
  #pragma unroll
  for (int j = 0; j < 10; ++j) {   // 10*64 = 640 = KEP
    int idx = lane + 64 * j;
    float v = (row < NIT && idx < NH1) ? er[idx] : 0.f;
    ss += v * v;
    embb[(size_t)row * KEP + idx] = (_Float16)v;
  }
  for (int o = 32; o > 0; o >>= 1) ss += __shfl_down(ss, o);
  if (lane == 0) esq[row] = ss;
}

// -------------------------------------------------- MFMA NT GEMM, 128x128x64
// Single-buffer 2-barrier loop; BK=64 (full 128B-line rows); T2 XOR swizzle
// (linear gld16 dest + XOR-permuted GLOBAL source chunk + XOR'd ds_read col,
// involution within each 128B row); T1 bijective XCD remap for L2 sharing.
// MODE 0: C1-partial = x(fp32, reg-staged+cvt) @ W1T^T, split-K (gridDim.z)
// MODE 2: C1-partial = xh(f16, gld16-staged)  @ W1T^T, split-K (gridDim.z)
// MODE 1: dist       = hsq[m] - 2*(h3 @ emb^T) + esq[n]  -> d_out
template <int MODE>
__global__ __launch_bounds__(256, 4) void mfma_nt_k(
    const void* __restrict__ Av, const _Float16* __restrict__ Bg,
    float* __restrict__ Cout, const float* __restrict__ hsq,
    const float* __restrict__ esq) {
  __shared__ _Float16 As[128 * 64];
  __shared__ _Float16 Bs[128 * 64];

  const int t = threadIdx.x;

  // ---- T1 XCD remap (hw: consecutive flat ids round-robin XCDs; remap so
  // each XCD gets a contiguous chunk of work, sharers co-located on one L2)
  int n0, m0, ki0, ki1, zslab = 0, lda, ldb;
  if (MODE == 1) {
    int flat = blockIdx.x + NBLK4 * blockIdx.y;     // grid (391, 8); 3128 % 8 == 0
    int W = (flat & 7) * (NBLK4 * 8 / 8) + (flat >> 3);
    m0 = (W & 7) * 128;        // m fastest: 8 consecutive blocks share B n-slice
    n0 = (W >> 3) * 128;
    ki0 = 0; ki1 = KEP / 64;   // 10
    lda = KEP; ldb = KEP;
  } else {
    const int S = (int)gridDim.z;
    int flat = blockIdx.x + NBLK1 * (blockIdx.y + 8 * blockIdx.z);  // nwg = 40*S, %8==0
    int W = (flat & 7) * (5 * S) + (flat >> 3);
    int xq = W % 5;
    int yz = W / 5;
    n0 = xq * 128;             // x fastest: 5 consecutive blocks share A m-slice
    m0 = (yz & 7) * 128;
    zslab = yz >> 3;
    int kiPer = (KI64_TOTAL + S - 1) / S;
    ki0 = zslab * kiPer;
    ki1 = ki0 + kiPer; if (ki1 > KI64_TOTAL) ki1 = KI64_TOTAL;
    lda = (MODE == 0) ? NIT : KXP;
    ldb = KXP;
  }

  const int lane = t & 63;
  const int wid = t >> 6;
  const int wm = wid >> 1, wn = wid & 1;
  const int lrow = lane & 15, quad = lane >> 4;

  const f32x4 zero = {0.f, 0.f, 0.f, 0.f};
  f32x4 acc[4][4];
  #pragma unroll
  for (int i = 0; i < 4; ++i)
    #pragma unroll
    for (int j = 0; j < 4; ++j) acc[i][j] = zero;

  for (int ki = ki0; ki < ki1; ++ki) {
    const int k0 = ki * 64;
    // ---- stage A tile [128 rows][64 k] ----
    if (MODE == 0) {
      const float* A = (const float*)Av;
      #pragma unroll
      for (int j = 0; j < 8; ++j) {
        int g = j * 256 + t;          // 0..2047 float4 units
        int row = g >> 4;             // 0..127
        int q4 = g & 15;              // float4 within row
        int kcol = k0 + q4 * 4;
        float4 v = {0.f, 0.f, 0.f, 0.f};
        if (kcol < NIT)
          v = *(const float4*)(A + (size_t)(m0 + row) * lda + kcol);
        f16x4 h;
        h.x = (_Float16)v.x; h.y = (_Float16)v.y;
        h.z = (_Float16)v.z; h.w = (_Float16)v.w;
        int c16 = (q4 >> 1) ^ (row & 7);   // swizzled 16B-chunk col
        *(f16x4*)(&As[row * 64 + c16 * 8 + (q4 & 1) * 4]) = h;
      }
    } else {
      const _Float16* A = (const _Float16*)Av;
      #pragma unroll
      for (int j = 0; j < 4; ++j) {
        int c = j * 256 + t;          // 16B-chunk id, 0..1023
        int row = c >> 3;             // 0..127
        int kk = ((c & 7) ^ (row & 7)) << 3;  // XOR-permuted SOURCE k (f16)
        gld16(A + (size_t)(m0 + row) * lda + (k0 + kk), &As[c * 8]);
      }
    }
    // ---- stage B tile [128 n][64 k] ----
    #pragma unroll
    for (int j = 0; j < 4; ++j) {
      int c = j * 256 + t;
      int row = c >> 3;
      int kk = ((c & 7) ^ (row & 7)) << 3;
      gld16(Bg + (size_t)(n0 + row) * ldb + (k0 + kk), &Bs[c * 8]);
    }
    __syncthreads();

    // ---- two 32-k slices per staged tile ----
    #pragma unroll
    for (int ks = 0; ks < 2; ++ks) {
      f16x8 af[4], bfr[4];
      #pragma unroll
      for (int mi = 0; mi < 4; ++mi) {
        int row = wm * 64 + mi * 16 + lrow;
        int c16 = (ks * 4 + quad) ^ (lrow & 7);   // row&7 == lrow&7 here
        af[mi] = *(const f16x8*)(&As[row * 64 + c16 * 8]);
      }
      #pragma unroll
      for (int ni = 0; ni < 4; ++ni) {
        int row = wn * 64 + ni * 16 + lrow;
        int c16 = (ks * 4 + quad) ^ (lrow & 7);
        bfr[ni] = *(const f16x8*)(&Bs[row * 64 + c16 * 8]);
      }
      #pragma unroll
      for (int mi = 0; mi < 4; ++mi)
        #pragma unroll
        for (int ni = 0; ni < 4; ++ni)
          acc[mi][ni] = __builtin_amdgcn_mfma_f32_16x16x32_f16(af[mi], bfr[ni],
                                                               acc[mi][ni], 0, 0, 0);
    }
    __syncthreads();
  }

  // ---- epilogue; C/D layout: col = lane&15, row = (lane>>4)*4 + reg ----
  if (MODE != 1) {
    float* Cs = Cout + (size_t)zslab * BROWS * N1P;
    #pragma unroll
    for (int mi = 0; mi < 4; ++mi)
      #pragma unroll
      for (int r = 0; r < 4; ++r) {
        int row = m0 + wm * 64 + mi * 16 + quad * 4 + r;
        #pragma unroll
        for (int ni = 0; ni < 4; ++ni) {
          int col = n0 + wn * 64 + ni * 16 + lrow;
          Cs[(size_t)row * N1P + col] = acc[mi][ni][r];
        }
      }
  } else {
    #pragma unroll
    for (int mi = 0; mi < 4; ++mi)
      #pragma unroll
      for (int r = 0; r < 4; ++r) {
        int row = m0 + wm * 64 + mi * 16 + quad * 4 + r;
        float hv = hsq[row];
        #pragma unroll
        for (int ni = 0; ni < 4; ++ni) {
          int col = n0 + wn * 64 + ni * 16 + lrow;
          if (col < NIT)
            Cout[(size_t)row * NIT + col] = hv - 2.f * acc[mi][ni][r] + esq[col];
        }
      }
  }
}

// ------------------------- sum split-K slabs, scale by invnorm, +b1, tanh
__global__ __launch_bounds__(256) void reduce_epi1_k(const float* __restrict__ C1p,
                                                     const float* __restrict__ invnorm,
                                                     const float* __restrict__ b1,
                                                     float* __restrict__ h1,
                                                     int nslabs) {
  int idx = blockIdx.x * 256 + threadIdx.x;
  if (idx >= BROWS * NH1) return;
  int m = idx / NH1, n = idx - m * NH1;
  float s = 0.f;
  for (int sp = 0; sp < nslabs; ++sp)
    s += C1p[(size_t)sp * BROWS * N1P + (size_t)m * N1P + n];
  h1[idx] = tanhf(invnorm[m] * s + b1[n]);
}

// ------------------------------------------------ h2 = tanh(h1 @ W2 + b2)
__global__ __launch_bounds__(256) void gemm2_k(const float* __restrict__ h1,
                                               const float* __restrict__ W2,
                                               const float* __restrict__ b2,
                                               float* __restrict__ h2) {
  __shared__ float hs[8 * NH1];
  const int m0 = blockIdx.x * 8;
  const int t = threadIdx.x;
  for (int i = t; i < 8 * NH1; i += 256) hs[i] = h1[(size_t)m0 * NH1 + i];
  __syncthreads();
  if (t < NH2) {
    float acc[8];
    #pragma unroll
    for (int r = 0; r < 8; ++r) acc[r] = 0.f;
    for (int k0 = 0; k0 < NH1; k0 += 8) {   // 600 = 75 * 8
      float w[8];
      #pragma unroll
      for (int u = 0; u < 8; ++u) w[u] = W2[(k0 + u) * NH2 + t];
      #pragma unroll
      for (int u = 0; u < 8; ++u)
        #pragma unroll
        for (int r = 0; r < 8; ++r) acc[r] += hs[r * NH1 + k0 + u] * w[u];
    }
    float bb = b2[t];
    #pragma unroll
    for (int r = 0; r < 8; ++r) h2[(size_t)(m0 + r) * NH2 + t] = tanhf(acc[r] + bb);
  }
}

// --------------------- h3 = tanh(h2 @ W3 + b3) -> f16 [BROWS][KEP] + hsq
__global__ __launch_bounds__(256) void gemm3_k(const float* __restrict__ h2,
                                               const float* __restrict__ W3,
                                               const float* __restrict__ b3,
                                               _Float16* __restrict__ h3h,
                                               float* __restrict__ hsq) {
  __shared__ float hs[8 * NH2];
  const int m0 = blockIdx.x * 8;
  const int t = threadIdx.x;
  for (int i = t; i < 8 * NH2; i += 256) hs[i] = h2[(size_t)m0 * NH2 + i];
  __syncthreads();
  float ssq[8];
  #pragma unroll
  for (int r = 0; r < 8; ++r) ssq[r] = 0.f;
  for (int c = 0; c < 3; ++c) {
    int n = t + c * 256;
    if (n < NH1) {
      float acc[8];
      #pragma unroll
      for (int r = 0; r < 8; ++r) acc[r] = 0.f;
      for (int k0 = 0; k0 < NH2; k0 += 8) {  // 200 = 25 * 8
        float w[8];
        #pragma unroll
        for (int u = 0; u < 8; ++u) w[u] = W3[(k0 + u) * NH1 + n];
        #pragma unroll
        for (int u = 0; u < 8; ++u)
          #pragma unroll
          for (int r = 0; r < 8; ++r) acc[r] += hs[r * NH2 + k0 + u] * w[u];
      }
      float bb = b3[n];
      #pragma unroll
      for (int r = 0; r < 8; ++r) {
        float v = tanhf(acc[r] + bb);
        h3h[(size_t)(m0 + r) * KEP + n] = (_Float16)v;
        ssq[r] += v * v;
      }
    } else if (n < KEP) {
      #pragma unroll
      for (int r = 0; r < 8; ++r) h3h[(size_t)(m0 + r) * KEP + n] = (_Float16)0.f;
    }
  }
  const int lane = t & 63, wid = t >> 6;
  #pragma unroll
  for (int r = 0; r < 8; ++r)
    for (int o = 32; o > 0; o >>= 1) ssq[r] += __shfl_down(ssq[r], o);
  __shared__ float red2[8][4];
  if (lane == 0) {
    #pragma unroll
    for (int r = 0; r < 8; ++r) red2[r][wid] = ssq[r];
  }
  __syncthreads();
  if (t < 8) hsq[m0 + t] = red2[t][0] + red2[t][1] + red2[t][2] + red2[t][3];
}

}  // namespace

extern "C" void kernel_launch(void* const* d_in, const int* in_sizes, int n_in,
                              void* d_out, int out_size, void* d_ws, size_t ws_size,
                              hipStream_t stream) {
  const float* x   = (const float*)d_in[0];
  const float* W1  = (const float*)d_in[1];
  const float* b1  = (const float*)d_in[2];
  const float* W2  = (const float*)d_in[3];
  const float* b2  = (const float*)d_in[4];
  const float* W3  = (const float*)d_in[5];
  const float* b3  = (const float*)d_in[6];
  const float* emb = (const float*)d_in[7];
  float* out = (float*)d_out;

  char* ws = (char*)d_ws;

  // sizes (all multiples of 256B)
  const size_t XHSZ  = (size_t)BROWS * KXP * 2;   // 102,498,304 (f16 x, k-padded)
  const size_t W1TSZ = (size_t)N1P * KXP * 2;     //  64,061,440
  const size_t SLAB  = (size_t)BROWS * N1P * 4;   //   2,621,440 per split slab
  const size_t TAIL  = 4096 + 200192 + 2457600 + 819200 + 1310720 + 4096;

  bool useF16A;
  int S;
  const size_t baseA = XHSZ + W1TSZ + TAIL;   // ~171.4 MB
  const size_t baseB = W1TSZ + TAIL;          //  ~68.9 MB
  if (ws_size >= baseA + 16 * SLAB) {
    useF16A = true;
    size_t s = (ws_size - baseA) / SLAB;
    S = s > 32 ? 32 : (int)s;
  } else if (ws_size >= baseB + 8 * SLAB) {
    useF16A = false;
    size_t s = (ws_size - baseB) / SLAB;
    S = s > 32 ? 32 : (int)s;
  } else {
    return;  // ws too small -> fail visibly (poison output)
  }

  size_t off = 0;
  _Float16* xh = nullptr;
  if (useF16A) { xh = (_Float16*)(ws + off); off += XHSZ; }
  const size_t oW1T = off;
  _Float16* W1T = (_Float16*)(ws + off); off += W1TSZ;
  float* C1p = (float*)(ws + off); off += (size_t)S * SLAB;
  float* invn = (float*)(ws + off); off += 4096;
  float* esq  = (float*)(ws + off); off += 200192;
  float* h1   = (float*)(ws + off); off += 2457600;
  float* h2   = (float*)(ws + off); off += 819200;
  _Float16* h3h = (_Float16*)(ws + off); off += 1310720;
  float* hsq  = (float*)(ws + off); off += 4096;
  _Float16* embb = (_Float16*)(ws + oW1T);  // aliases W1T (dead after gemm1);
                                            // NEP*KEP*2 == N1P*KXP*2 exactly

  norm_conv_k<<<dim3(BROWS), dim3(256), 0, stream>>>(x, invn, xh);
  transpose_w1_k<<<dim3(KXP / 64, N1P / 64), dim3(256), 0, stream>>>(W1, W1T);
  if (useF16A) {
    mfma_nt_k<2><<<dim3(NBLK1, BROWS / 128, S), dim3(256), 0, stream>>>(
        (const void*)xh, W1T, C1p, nullptr, nullptr);
  } else {
    mfma_nt_k<0><<<dim3(NBLK1, BROWS / 128, S), dim3(256), 0, stream>>>(
        (const void*)x, W1T, C1p, nullptr, nullptr);
  }
  reduce_epi1_k<<<dim3((BROWS * NH1 + 255) / 256), dim3(256), 0, stream>>>(
      C1p, invn, b1, h1, S);
  prep_emb_k<<<dim3(NEP / 4), dim3(256), 0, stream>>>(emb, embb, esq);
  gemm2_k<<<dim3(BROWS / 8), dim3(256), 0, stream>>>(h1, W2, b2, h2);
  gemm3_k<<<dim3(BROWS / 8), dim3(256), 0, stream>>>(h2, W3, b3, h3h, hsq);
  mfma_nt_k<1><<<dim3(NBLK4, BROWS / 128, 1), dim3(256), 0, stream>>>(
      (const void*)h3h, embb, out, hsq, esq);
}